// Round 3
// baseline (231.617 us; speedup 1.0000x reference)
//
#include <hip/hip_runtime.h>
#include <hip/hip_cooperative_groups.h>
#include <cstdint>

namespace cg = cooperative_groups;

#define NPTS 65536
#define CCH  1024
#define BSEG 256
#define KSLOT 512

typedef float v4f __attribute__((ext_vector_type(4)));

struct Params {
  const float* feat; const float* info; const int* offs;
  const float* W1; const float* b1; const float* ln1_g; const float* ln1_b;
  const float* Wi; const float* bi;
  const float* Wa1; const float* ba1; const float* lna_g; const float* lna_b;
  const float* Wa2; const float* ba2;
  const float* Wo1; const float* bo1; const float* lno_g; const float* lno_b;
  const float* Wo2; const float* bo2;
  unsigned* keys; float* part1; float* part2; float* xbuf;
  float* out;
};

// monotonic float -> unsigned key; identity is 0 (every real float maps > 0)
__device__ __forceinline__ unsigned ukey(float f) {
  int i = __float_as_int(f);
  return i >= 0 ? ((unsigned)i | 0x80000000u) : ~(unsigned)i;
}
__device__ __forceinline__ float udec(unsigned u, bool rl) {
  float v;
  if (u >= 0x80000000u) v = __int_as_float((int)(u & 0x7FFFFFFFu));
  else                  v = __int_as_float((int)~u);
  if (u == 0u) v = -__builtin_inff();   // empty segment
  if (rl) v = fmaxf(v, 0.0f);
  return v;
}
__device__ __forceinline__ v4f vmax4(v4f a, v4f b) {
  v4f r;
  r.x = fmaxf(a.x, b.x); r.y = fmaxf(a.y, b.y);
  r.z = fmaxf(a.z, b.z); r.w = fmaxf(a.w, b.w);
  return r;
}

__global__ __launch_bounds__(256) void mega_k(Params P) {
  cg::grid_group grid = cg::this_grid();
  const int b = blockIdx.x;   // 0..255
  const int t = threadIdx.x;  // 0..255

  __shared__ float As[32][68];
  __shared__ float Ws[32][68];
  __shared__ float hbuf[512];
  __shared__ float sred[16];
  __shared__ float sstats[4];

  // ================= Phase Z: zero keys =================
  {
    unsigned* kp = P.keys + (size_t)b * 1024 + t * 4;
    *(uint4*)kp = make_uint4(0u, 0u, 0u, 0u);
  }
  grid.sync();

  // ================= Phase S: segment max over feat rows [b*256, b*256+256) =================
  {
    int col = t << 2;
    int row0 = b << 8;
    int row_end = row0 + 256;
    int lo = 0, hi = BSEG - 1;
    while (lo < hi) { int mid = (lo + hi) >> 1; if (P.offs[mid] > row0) hi = mid; else lo = mid + 1; }
    int seg = lo;
    int end = P.offs[seg];
    const float NI = -__builtin_inff();
    v4f m; m.x = NI; m.y = NI; m.z = NI; m.w = NI;
    bool dirty = false;
    int r = row0;
    while (r < row_end) {
      while (r >= end) {
        if (dirty) {
          unsigned* kp = P.keys + (size_t)seg * CCH + col;
          atomicMax(kp + 0, ukey(m.x));
          atomicMax(kp + 1, ukey(m.y));
          atomicMax(kp + 2, ukey(m.z));
          atomicMax(kp + 3, ukey(m.w));
          m.x = NI; m.y = NI; m.z = NI; m.w = NI;
          dirty = false;
        }
        ++seg;
        end = P.offs[seg];
      }
      int stop = min(row_end, end);
      const float* p = P.feat + (size_t)r * CCH + col;
      for (; r + 16 <= stop; r += 16) {
        v4f v[16];
#pragma unroll
        for (int j = 0; j < 16; ++j) v[j] = *(const v4f*)(p + (size_t)j * CCH);
        p += 16 * CCH;
#pragma unroll
        for (int d = 8; d; d >>= 1)
#pragma unroll
          for (int j = 0; j < d; ++j) v[j] = vmax4(v[j], v[j + d]);
        m = vmax4(m, v[0]);
      }
      for (; r < stop; ++r) {
        v4f v = *(const v4f*)(p);
        p += CCH;
        m = vmax4(m, v);
      }
      dirty = true;
    }
    if (dirty) {
      unsigned* kp = P.keys + (size_t)seg * CCH + col;
      atomicMax(kp + 0, ukey(m.x));
      atomicMax(kp + 1, ukey(m.y));
      atomicMax(kp + 2, ukey(m.z));
      atomicMax(kp + 3, ukey(m.w));
    }
  }
  grid.sync();

  // ================= Phase A: GEMM1 (decode keys -> A; write features; part1 8 K-slabs) =====
  {
    int bx = b & 7, by = (b >> 3) & 3, bz = b >> 5;   // 8 x 4 x 8
    int tx = t & 15, ty = t >> 4;
    int lr = t >> 3;          // 0..31
    int lk = (t & 7) << 2;    // 0,4,...,28
    int row0 = by * 64 + lr, row1 = row0 + 32;
    int len0 = P.offs[row0] - (row0 ? P.offs[row0 - 1] : 0);
    int len1 = P.offs[row1] - P.offs[row1 - 1];
    bool rl0 = len0 < KSLOT, rl1 = len1 < KSLOT;
    const unsigned* K0 = P.keys + (size_t)row0 * CCH + lk;
    const unsigned* K1 = P.keys + (size_t)row1 * CCH + lk;
    int c0 = bx * 64 + lr, c1 = c0 + 32;
    const float* Wr0 = P.W1 + (size_t)c0 * CCH + lk;
    const float* Wr1 = P.W1 + (size_t)c1 * CCH + lk;
    float acc[4][4] = {};
    for (int s = 0; s < 4; ++s) {
      int k0 = (bz * 4 + s) << 5;
      uint4 ua = *(const uint4*)(K0 + k0);
      uint4 ub = *(const uint4*)(K1 + k0);
      float4 w0 = *(const float4*)(Wr0 + k0);
      float4 w1 = *(const float4*)(Wr1 + k0);
      float4 a0 = make_float4(udec(ua.x, rl0), udec(ua.y, rl0), udec(ua.z, rl0), udec(ua.w, rl0));
      float4 a1 = make_float4(udec(ub.x, rl1), udec(ub.y, rl1), udec(ub.z, rl1), udec(ub.w, rl1));
      if (bx == 0) {
        *(float4*)(P.out + (size_t)row0 * CCH + k0 + lk) = a0;
        *(float4*)(P.out + (size_t)row1 * CCH + k0 + lk) = a1;
      }
      __syncthreads();
      As[lk + 0][lr] = a0.x; As[lk + 1][lr] = a0.y; As[lk + 2][lr] = a0.z; As[lk + 3][lr] = a0.w;
      As[lk + 0][lr + 32] = a1.x; As[lk + 1][lr + 32] = a1.y; As[lk + 2][lr + 32] = a1.z; As[lk + 3][lr + 32] = a1.w;
      Ws[lk + 0][lr] = w0.x; Ws[lk + 1][lr] = w0.y; Ws[lk + 2][lr] = w0.z; Ws[lk + 3][lr] = w0.w;
      Ws[lk + 0][lr + 32] = w1.x; Ws[lk + 1][lr + 32] = w1.y; Ws[lk + 2][lr + 32] = w1.z; Ws[lk + 3][lr + 32] = w1.w;
      __syncthreads();
#pragma unroll
      for (int kk = 0; kk < 32; ++kk) {
        float4 av = *(const float4*)&As[kk][ty << 2];
        float4 wv = *(const float4*)&Ws[kk][tx << 2];
        acc[0][0] += av.x * wv.x; acc[0][1] += av.x * wv.y; acc[0][2] += av.x * wv.z; acc[0][3] += av.x * wv.w;
        acc[1][0] += av.y * wv.x; acc[1][1] += av.y * wv.y; acc[1][2] += av.y * wv.z; acc[1][3] += av.y * wv.w;
        acc[2][0] += av.z * wv.x; acc[2][1] += av.z * wv.y; acc[2][2] += av.z * wv.z; acc[2][3] += av.z * wv.w;
        acc[3][0] += av.w * wv.x; acc[3][1] += av.w * wv.y; acc[3][2] += av.w * wv.z; acc[3][3] += av.w * wv.w;
      }
    }
    float* op = P.part1 + (size_t)bz * 131072 + (size_t)(by * 64 + (ty << 2)) * 512 + bx * 64 + (tx << 2);
#pragma unroll
    for (int i = 0; i < 4; ++i)
      *(float4*)(op + (size_t)i * 512) = make_float4(acc[i][0], acc[i][1], acc[i][2], acc[i][3]);
  }
  grid.sync();

  // ================= Phase B: sum 8 slabs + bias -> LN(512) -> ReLU -> x; info layer ========
  {
    int wv = t >> 6, ln = t & 63;
    const float* p = P.part1 + (size_t)b * 512;
    float z0 = P.b1[t], z1 = P.b1[t + 256];
#pragma unroll
    for (int j = 0; j < 8; ++j) {
      z0 += p[(size_t)j * 131072 + t];
      z1 += p[(size_t)j * 131072 + t + 256];
    }
    float s = z0 + z1, q = z0 * z0 + z1 * z1;
#pragma unroll
    for (int o = 32; o; o >>= 1) { s += __shfl_down(s, o); q += __shfl_down(q, o); }
    if (ln == 0) { sred[wv] = s; sred[4 + wv] = q; }
    __syncthreads();
    if (t == 0) {
      float S = sred[0] + sred[1] + sred[2] + sred[3];
      float Q = sred[4] + sred[5] + sred[6] + sred[7];
      float mean = S * (1.f / 512.f);
      float var = Q * (1.f / 512.f) - mean * mean;
      sstats[0] = mean; sstats[1] = rsqrtf(var + 1e-5f);
    }
    __syncthreads();
    float mean = sstats[0], rstd = sstats[1];
    P.xbuf[b * 544 + t]       = fmaxf((z0 - mean) * rstd * P.ln1_g[t]       + P.ln1_b[t],       0.f);
    P.xbuf[b * 544 + t + 256] = fmaxf((z1 - mean) * rstd * P.ln1_g[t + 256] + P.ln1_b[t + 256], 0.f);
    if (t < 32) {
      float i0 = P.info[b * 3], i1 = P.info[b * 3 + 1], i2 = P.info[b * 3 + 2];
      P.xbuf[b * 544 + 512 + t] = P.bi[t] + P.Wi[t * 3] * i0 + P.Wi[t * 3 + 1] * i1 + P.Wi[t * 3 + 2] * i2;
    }
  }
  grid.sync();

  // ================= Phase C: GEMM2 x(256x544) @ [Wa1;Wo1]^T, part2 6 K-slabs ==============
  if (b < 192) {
    int bx = b & 7, by = (b >> 3) & 3, bz = b >> 5;   // 8 x 4 x 6
    int tx = t & 15, ty = t >> 4;
    int lr = t >> 3;
    int lk = (t & 7) << 2;
    int step0 = bz * 3;
    int nsteps = min(3, 17 - step0);
    const float* Arow0 = P.xbuf + (size_t)(by * 64 + lr) * 544 + lk;
    const float* Arow1 = Arow0 + (size_t)32 * 544;
    int c0 = bx * 64 + lr, c1 = c0 + 32;
    const float* Wrow0 = (c0 < 256 ? P.Wa1 + (size_t)c0 * 544 : P.Wo1 + (size_t)(c0 - 256) * 544) + lk;
    const float* Wrow1 = (c1 < 256 ? P.Wa1 + (size_t)c1 * 544 : P.Wo1 + (size_t)(c1 - 256) * 544) + lk;
    float acc[4][4] = {};
    for (int s = 0; s < nsteps; ++s) {
      int k0 = (step0 + s) << 5;
      float4 a0 = *(const float4*)(Arow0 + k0);
      float4 a1 = *(const float4*)(Arow1 + k0);
      float4 w0 = *(const float4*)(Wrow0 + k0);
      float4 w1 = *(const float4*)(Wrow1 + k0);
      __syncthreads();
      As[lk + 0][lr] = a0.x; As[lk + 1][lr] = a0.y; As[lk + 2][lr] = a0.z; As[lk + 3][lr] = a0.w;
      As[lk + 0][lr + 32] = a1.x; As[lk + 1][lr + 32] = a1.y; As[lk + 2][lr + 32] = a1.z; As[lk + 3][lr + 32] = a1.w;
      Ws[lk + 0][lr] = w0.x; Ws[lk + 1][lr] = w0.y; Ws[lk + 2][lr] = w0.z; Ws[lk + 3][lr] = w0.w;
      Ws[lk + 0][lr + 32] = w1.x; Ws[lk + 1][lr + 32] = w1.y; Ws[lk + 2][lr + 32] = w1.z; Ws[lk + 3][lr + 32] = w1.w;
      __syncthreads();
#pragma unroll
      for (int kk = 0; kk < 32; ++kk) {
        float4 av = *(const float4*)&As[kk][ty << 2];
        float4 wv = *(const float4*)&Ws[kk][tx << 2];
        acc[0][0] += av.x * wv.x; acc[0][1] += av.x * wv.y; acc[0][2] += av.x * wv.z; acc[0][3] += av.x * wv.w;
        acc[1][0] += av.y * wv.x; acc[1][1] += av.y * wv.y; acc[1][2] += av.y * wv.z; acc[1][3] += av.y * wv.w;
        acc[2][0] += av.z * wv.x; acc[2][1] += av.z * wv.y; acc[2][2] += av.z * wv.z; acc[2][3] += av.z * wv.w;
        acc[3][0] += av.w * wv.x; acc[3][1] += av.w * wv.y; acc[3][2] += av.w * wv.z; acc[3][3] += av.w * wv.w;
      }
    }
    float* op = P.part2 + (size_t)bz * 131072 + (size_t)(by * 64 + (ty << 2)) * 512 + bx * 64 + (tx << 2);
#pragma unroll
    for (int i = 0; i < 4; ++i)
      *(float4*)(op + (size_t)i * 512) = make_float4(acc[i][0], acc[i][1], acc[i][2], acc[i][3]);
  }
  grid.sync();

  // ================= Phase D: sum 6 slabs -> LN(256) x2 -> ReLU -> heads ====================
  {
    int wv = t >> 6, ln = t & 63;
    const float* p0 = P.part2 + (size_t)b * 512;
    float za = P.ba1[t], zo = P.bo1[t];
#pragma unroll
    for (int j = 0; j < 6; ++j) {
      za += p0[(size_t)j * 131072 + t];
      zo += p0[(size_t)j * 131072 + 256 + t];
    }
    float sa = za, qa = za * za, so = zo, qo = zo * zo;
#pragma unroll
    for (int o = 32; o; o >>= 1) {
      sa += __shfl_down(sa, o); qa += __shfl_down(qa, o);
      so += __shfl_down(so, o); qo += __shfl_down(qo, o);
    }
    if (ln == 0) { sred[wv] = sa; sred[4 + wv] = qa; sred[8 + wv] = so; sred[12 + wv] = qo; }
    __syncthreads();
    if (t == 0) {
      float Sa = sred[0] + sred[1] + sred[2] + sred[3];
      float Qa = sred[4] + sred[5] + sred[6] + sred[7];
      float So = sred[8] + sred[9] + sred[10] + sred[11];
      float Qo = sred[12] + sred[13] + sred[14] + sred[15];
      float ma = Sa * (1.f / 256.f), va = Qa * (1.f / 256.f) - ma * ma;
      float mo = So * (1.f / 256.f), vo = Qo * (1.f / 256.f) - mo * mo;
      sstats[0] = ma; sstats[1] = rsqrtf(va + 1e-5f);
      sstats[2] = mo; sstats[3] = rsqrtf(vo + 1e-5f);
    }
    __syncthreads();
    hbuf[t]       = fmaxf((za - sstats[0]) * sstats[1] * P.lna_g[t] + P.lna_b[t], 0.f);
    hbuf[256 + t] = fmaxf((zo - sstats[2]) * sstats[3] * P.lno_g[t] + P.lno_b[t], 0.f);
    __syncthreads();
    const float* hh = (wv == 0) ? hbuf : (hbuf + 256);
    const float* W2 = (wv == 0) ? P.Wa2 : P.Wo2;
    const float* b2 = (wv == 0) ? P.ba2 : P.bo2;
    int o0 = (wv == 0) ? 0 : (wv - 1) * 6;
    int base = (wv == 0) ? (262144 + b * 6) : (263680 + b * 18);
    float h0 = hh[ln], h1 = hh[64 + ln], h2v = hh[128 + ln], h3 = hh[192 + ln];
#pragma unroll
    for (int oo = 0; oo < 6; ++oo) {
      int o = o0 + oo;
      const float* w = W2 + o * 256;
      float pr = h0 * w[ln] + h1 * w[64 + ln] + h2v * w[128 + ln] + h3 * w[192 + ln];
#pragma unroll
      for (int d = 32; d; d >>= 1) pr += __shfl_down(pr, d);
      if (ln == 0) P.out[base + o] = pr + b2[o];
    }
  }
}

extern "C" void kernel_launch(void* const* d_in, const int* in_sizes, int n_in,
                              void* d_out, int out_size, void* d_ws, size_t ws_size,
                              hipStream_t stream) {
  char* ws = (char*)d_ws;
  Params P;
  P.feat  = (const float*)d_in[0];
  P.info  = (const float*)d_in[1];
  P.offs  = (const int*)d_in[2];
  P.W1    = (const float*)d_in[3];
  P.b1    = (const float*)d_in[4];
  P.ln1_g = (const float*)d_in[5];
  P.ln1_b = (const float*)d_in[6];
  P.Wi    = (const float*)d_in[7];
  P.bi    = (const float*)d_in[8];
  P.Wa1   = (const float*)d_in[9];
  P.ba1   = (const float*)d_in[10];
  P.lna_g = (const float*)d_in[11];
  P.lna_b = (const float*)d_in[12];
  P.Wa2   = (const float*)d_in[13];
  P.ba2   = (const float*)d_in[14];
  P.Wo1   = (const float*)d_in[15];
  P.bo1   = (const float*)d_in[16];
  P.lno_g = (const float*)d_in[17];
  P.lno_b = (const float*)d_in[18];
  P.Wo2   = (const float*)d_in[19];
  P.bo2   = (const float*)d_in[20];
  P.part1 = (float*)(ws);                    // 8*256*512*4 = 4 MB
  P.part2 = (float*)(ws + (4u << 20));       // 6*256*512*4 = 3 MB
  P.xbuf  = (float*)(ws + (7u << 20));       // 256*544*4 ≈ 557 KB
  P.keys  = (unsigned*)(ws + (8u << 20));    // 256*1024*4 = 1 MB
  P.out   = (float*)d_out;

  void* args[] = { &P };
  hipLaunchCooperativeKernel(mega_k, dim3(256), dim3(256), args, 0, stream);
}

// Round 4
// 124.234 us; speedup vs baseline: 1.8644x; 1.8644x over previous
//
#include <hip/hip_runtime.h>
#include <cstdint>

#define NPTS 65536
#define CCH  1024
#define BSEG 256
#define KSLOT 512
#define WROWS 64   // rows per segmax block window

typedef float v4f __attribute__((ext_vector_type(4)));

// monotonic float -> unsigned key; identity element is 0 (every real float maps > 0)
__device__ __forceinline__ unsigned ukey(float f) {
  int i = __float_as_int(f);
  return i >= 0 ? ((unsigned)i | 0x80000000u) : ~(unsigned)i;
}
// decode + apply the "len<K -> max(x,0)" padding rule; u==0 (empty segment) -> -inf -> relu -> 0
__device__ __forceinline__ float udec(unsigned u, bool rl) {
  float v;
  if (u >= 0x80000000u) v = __int_as_float((int)(u & 0x7FFFFFFFu));
  else                  v = __int_as_float((int)~u);
  if (u == 0u) v = -__builtin_inff();
  if (rl) v = fmaxf(v, 0.0f);
  return v;
}
__device__ __forceinline__ v4f vmax4(v4f a, v4f b) {
  v4f r;
  r.x = fmaxf(a.x, b.x); r.y = fmaxf(a.y, b.y);
  r.z = fmaxf(a.z, b.z); r.w = fmaxf(a.w, b.w);
  return r;
}

// 1024 blocks x 256 threads (4 blocks/CU, 16 waves/CU); 64-row window, 8-deep float4 unroll.
__global__ __launch_bounds__(256) void segmax_k(const float* __restrict__ feat,
                                                const int* __restrict__ offsets,
                                                unsigned* __restrict__ keys) {
  int t = threadIdx.x;
  int col = t << 2;
  int row0 = blockIdx.x * WROWS;
  int row_end = row0 + WROWS;
  // first seg with offsets[seg] > row0
  int lo = 0, hi = BSEG - 1;
  while (lo < hi) { int mid = (lo + hi) >> 1; if (offsets[mid] > row0) hi = mid; else lo = mid + 1; }
  int seg = lo;
  int end = offsets[seg];
  const float NI = -__builtin_inff();
  v4f m; m.x = NI; m.y = NI; m.z = NI; m.w = NI;
  bool dirty = false;
  int r = row0;
  while (r < row_end) {
    while (r >= end) {
      if (dirty) {
        unsigned* kp = keys + (size_t)seg * CCH + col;
        atomicMax(kp + 0, ukey(m.x));
        atomicMax(kp + 1, ukey(m.y));
        atomicMax(kp + 2, ukey(m.z));
        atomicMax(kp + 3, ukey(m.w));
        m.x = NI; m.y = NI; m.z = NI; m.w = NI;
        dirty = false;
      }
      ++seg;
      end = offsets[seg];
    }
    int stop = min(row_end, end);
    const float* p = feat + (size_t)r * CCH + col;
    for (; r + 8 <= stop; r += 8) {
      v4f v[8];
#pragma unroll
      for (int j = 0; j < 8; ++j) v[j] = *(const v4f*)(p + (size_t)j * CCH);
      p += 8 * CCH;
#pragma unroll
      for (int d = 4; d; d >>= 1)
#pragma unroll
        for (int j = 0; j < d; ++j) v[j] = vmax4(v[j], v[j + d]);
      m = vmax4(m, v[0]);
    }
    for (; r < stop; ++r) {
      v4f v = *(const v4f*)(p);
      p += CCH;
      m = vmax4(m, v);
    }
    dirty = true;
  }
  if (dirty) {
    unsigned* kp = keys + (size_t)seg * CCH + col;
    atomicMax(kp + 0, ukey(m.x));
    atomicMax(kp + 1, ukey(m.y));
    atomicMax(kp + 2, ukey(m.z));
    atomicMax(kp + 3, ukey(m.w));
  }
}

// GEMM1 fused with key-decode + features d_out write.
// grid (8,4,8): bx = 64-col tile, by = 64-row tile, bz = K-chunk (128 wide, 4 steps).
// bx==0 blocks write the decoded A slice (rows by*64..+64, cols bz*128..+128).
__global__ __launch_bounds__(256) void gemm1_fused(
    const unsigned* __restrict__ keys, const int* __restrict__ offsets,
    const float* __restrict__ W1, float* __restrict__ features,
    float* __restrict__ part1) {
  __shared__ float As[32][68];
  __shared__ float Ws[32][68];
  int bx = blockIdx.x, by = blockIdx.y, bz = blockIdx.z;
  int t = threadIdx.x;
  int tx = t & 15, ty = t >> 4;
  int lr = t >> 3;          // 0..31
  int lk = (t & 7) << 2;    // 0,4,...,28
  int row0 = by * 64 + lr, row1 = row0 + 32;
  int len0 = offsets[row0] - (row0 ? offsets[row0 - 1] : 0);
  int len1 = offsets[row1] - offsets[row1 - 1];
  bool rl0 = len0 < KSLOT, rl1 = len1 < KSLOT;
  const unsigned* K0 = keys + (size_t)row0 * CCH + lk;
  const unsigned* K1 = keys + (size_t)row1 * CCH + lk;
  int c0 = bx * 64 + lr, c1 = c0 + 32;
  const float* Wr0 = W1 + (size_t)c0 * CCH + lk;
  const float* Wr1 = W1 + (size_t)c1 * CCH + lk;
  float acc[4][4] = {};
  for (int s = 0; s < 4; ++s) {
    int k0 = (bz * 4 + s) << 5;
    uint4 ua = *(const uint4*)(K0 + k0);
    uint4 ub = *(const uint4*)(K1 + k0);
    float4 w0 = *(const float4*)(Wr0 + k0);
    float4 w1 = *(const float4*)(Wr1 + k0);
    float4 a0 = make_float4(udec(ua.x, rl0), udec(ua.y, rl0), udec(ua.z, rl0), udec(ua.w, rl0));
    float4 a1 = make_float4(udec(ub.x, rl1), udec(ub.y, rl1), udec(ub.z, rl1), udec(ub.w, rl1));
    if (bx == 0) {
      *(float4*)(features + (size_t)row0 * CCH + k0 + lk) = a0;
      *(float4*)(features + (size_t)row1 * CCH + k0 + lk) = a1;
    }
    __syncthreads();
    As[lk + 0][lr] = a0.x; As[lk + 1][lr] = a0.y; As[lk + 2][lr] = a0.z; As[lk + 3][lr] = a0.w;
    As[lk + 0][lr + 32] = a1.x; As[lk + 1][lr + 32] = a1.y; As[lk + 2][lr + 32] = a1.z; As[lk + 3][lr + 32] = a1.w;
    Ws[lk + 0][lr] = w0.x; Ws[lk + 1][lr] = w0.y; Ws[lk + 2][lr] = w0.z; Ws[lk + 3][lr] = w0.w;
    Ws[lk + 0][lr + 32] = w1.x; Ws[lk + 1][lr + 32] = w1.y; Ws[lk + 2][lr + 32] = w1.z; Ws[lk + 3][lr + 32] = w1.w;
    __syncthreads();
#pragma unroll
    for (int kk = 0; kk < 32; ++kk) {
      float4 av = *(const float4*)&As[kk][ty << 2];
      float4 wv = *(const float4*)&Ws[kk][tx << 2];
      acc[0][0] += av.x * wv.x; acc[0][1] += av.x * wv.y; acc[0][2] += av.x * wv.z; acc[0][3] += av.x * wv.w;
      acc[1][0] += av.y * wv.x; acc[1][1] += av.y * wv.y; acc[1][2] += av.y * wv.z; acc[1][3] += av.y * wv.w;
      acc[2][0] += av.z * wv.x; acc[2][1] += av.z * wv.y; acc[2][2] += av.z * wv.z; acc[2][3] += av.z * wv.w;
      acc[3][0] += av.w * wv.x; acc[3][1] += av.w * wv.y; acc[3][2] += av.w * wv.z; acc[3][3] += av.w * wv.w;
    }
  }
  float* op = part1 + (size_t)bz * 131072 + (size_t)(by * 64 + (ty << 2)) * 512 + bx * 64 + (tx << 2);
#pragma unroll
  for (int i = 0; i < 4; ++i)
    *(float4*)(op + (size_t)i * 512) = make_float4(acc[i][0], acc[i][1], acc[i][2], acc[i][3]);
}

// One block per (row, head): sum 8 part1 slabs -> LN(512)+ReLU + info -> x[544] (LDS)
// -> hidden 256 (wave-cooperative dots, coalesced W rows) -> LN(256)+ReLU -> 6/18 outputs.
__global__ __launch_bounds__(256) void tail_k(
    const float* __restrict__ part1, const float* __restrict__ b1,
    const float* __restrict__ g1, const float* __restrict__ be1,
    const float* __restrict__ info, const float* __restrict__ Wi, const float* __restrict__ bi,
    const float* __restrict__ Wa1, const float* __restrict__ ba1,
    const float* __restrict__ ga, const float* __restrict__ bea,
    const float* __restrict__ Wa2, const float* __restrict__ ba2,
    const float* __restrict__ Wo1, const float* __restrict__ bo1,
    const float* __restrict__ go, const float* __restrict__ beo,
    const float* __restrict__ Wo2, const float* __restrict__ bo2,
    float* __restrict__ out) {
  int bb = blockIdx.x;
  int r = bb >> 1, head = bb & 1;
  int t = threadIdx.x;
  int wv = t >> 6, ln = t & 63;
  __shared__ float x[544];
  __shared__ float h[256];
  __shared__ float sred[8];
  __shared__ float sst[2];

  // ---- phase 1: z = b1 + sum_j part1[j][r][:]; LN(512) -> relu -> x[0:512]; info -> x[512:544]
  {
    const float* p = part1 + (size_t)r * 512;
    float z0 = b1[t], z1 = b1[t + 256];
#pragma unroll
    for (int j = 0; j < 8; ++j) {
      z0 += p[(size_t)j * 131072 + t];
      z1 += p[(size_t)j * 131072 + 256 + t];
    }
    float s = z0 + z1, q = z0 * z0 + z1 * z1;
#pragma unroll
    for (int o = 32; o; o >>= 1) { s += __shfl_down(s, o); q += __shfl_down(q, o); }
    if (ln == 0) { sred[wv] = s; sred[4 + wv] = q; }
    __syncthreads();
    if (t == 0) {
      float S = sred[0] + sred[1] + sred[2] + sred[3];
      float Q = sred[4] + sred[5] + sred[6] + sred[7];
      float mean = S * (1.f / 512.f);
      float var = Q * (1.f / 512.f) - mean * mean;
      sst[0] = mean; sst[1] = rsqrtf(var + 1e-5f);
    }
    __syncthreads();
    float mean = sst[0], rstd = sst[1];
    x[t]       = fmaxf((z0 - mean) * rstd * g1[t]       + be1[t],       0.f);
    x[t + 256] = fmaxf((z1 - mean) * rstd * g1[t + 256] + be1[t + 256], 0.f);
    if (t < 32) {
      float i0 = info[r * 3], i1 = info[r * 3 + 1], i2 = info[r * 3 + 2];
      x[512 + t] = bi[t] + Wi[t * 3] * i0 + Wi[t * 3 + 1] * i1 + Wi[t * 3 + 2] * i2;
    }
  }
  __syncthreads();

  // ---- phase 2: hidden[256] = W @ x + bias (wave w computes outputs w*64..w*64+63)
  {
    const float* W  = head ? Wo1 : Wa1;
    const float* bs = head ? bo1 : ba1;
    int o = wv * 64;
    for (int i = 0; i < 64; ++i, ++o) {
      const float* wr = W + (size_t)o * 544;
      float pr = 0.f;
#pragma unroll
      for (int j = 0; j < 8; ++j) pr += wr[j * 64 + ln] * x[j * 64 + ln];
      if (ln < 32) pr += wr[512 + ln] * x[512 + ln];
#pragma unroll
      for (int d = 32; d; d >>= 1) pr += __shfl_down(pr, d);
      if (ln == 0) h[o] = pr + bs[o];
    }
  }
  __syncthreads();

  // ---- phase 2b: LN(256) + relu (in-place in h)
  {
    float hv = h[t];
    float s = hv, q = hv * hv;
#pragma unroll
    for (int o = 32; o; o >>= 1) { s += __shfl_down(s, o); q += __shfl_down(q, o); }
    if (ln == 0) { sred[wv] = s; sred[4 + wv] = q; }
    __syncthreads();
    if (t == 0) {
      float S = sred[0] + sred[1] + sred[2] + sred[3];
      float Q = sred[4] + sred[5] + sred[6] + sred[7];
      float mean = S * (1.f / 256.f);
      float var = Q * (1.f / 256.f) - mean * mean;
      sst[0] = mean; sst[1] = rsqrtf(var + 1e-5f);
    }
    __syncthreads();
    float hn = fmaxf((hv - sst[0]) * sst[1] * (head ? go : ga)[t] + (head ? beo : bea)[t], 0.f);
    h[t] = hn;
  }
  __syncthreads();

  // ---- phase 3: final 6 (head 0) / 18 (head 1) dot products
  {
    const float* W2 = head ? Wo2 : Wa2;
    const float* b2 = head ? bo2 : ba2;
    int nout = head ? 18 : 6;
    int base = head ? (263680 + r * 18) : (262144 + r * 6);
    for (int o = wv; o < nout; o += 4) {
      const float* wr = W2 + (size_t)o * 256;
      float pr = wr[ln] * h[ln] + wr[64 + ln] * h[64 + ln]
               + wr[128 + ln] * h[128 + ln] + wr[192 + ln] * h[192 + ln];
#pragma unroll
      for (int d = 32; d; d >>= 1) pr += __shfl_down(pr, d);
      if (ln == 0) out[base + o] = pr + b2[o];
    }
  }
}

extern "C" void kernel_launch(void* const* d_in, const int* in_sizes, int n_in,
                              void* d_out, int out_size, void* d_ws, size_t ws_size,
                              hipStream_t stream) {
  const float* feat   = (const float*)d_in[0];
  const float* info   = (const float*)d_in[1];
  const int*   offs   = (const int*)d_in[2];
  const float* W1     = (const float*)d_in[3];
  const float* b1     = (const float*)d_in[4];
  const float* ln1_g  = (const float*)d_in[5];
  const float* ln1_b  = (const float*)d_in[6];
  const float* Wi     = (const float*)d_in[7];
  const float* bi     = (const float*)d_in[8];
  const float* Wa1    = (const float*)d_in[9];
  const float* ba1    = (const float*)d_in[10];
  const float* lna_g  = (const float*)d_in[11];
  const float* lna_b  = (const float*)d_in[12];
  const float* Wa2    = (const float*)d_in[13];
  const float* ba2    = (const float*)d_in[14];
  const float* Wo1    = (const float*)d_in[15];
  const float* bo1    = (const float*)d_in[16];
  const float* lno_g  = (const float*)d_in[17];
  const float* lno_b  = (const float*)d_in[18];
  const float* Wo2    = (const float*)d_in[19];
  const float* bo2    = (const float*)d_in[20];

  char* ws = (char*)d_ws;
  float*    part1 = (float*)ws;                 // 8*256*512*4 = 4 MB
  unsigned* keys  = (unsigned*)(ws + (4u << 20)); // 256*1024*4 = 1 MB
  float* features = (float*)d_out;              // [0, 262144)
  float* outp     = (float*)d_out;              // pred @262144, offset @263680

  hipMemsetAsync(keys, 0, (size_t)BSEG * CCH * sizeof(unsigned), stream);
  segmax_k<<<dim3(NPTS / WROWS), dim3(256), 0, stream>>>(feat, offs, keys);
  gemm1_fused<<<dim3(8, 4, 8), dim3(256), 0, stream>>>(keys, offs, W1, features, part1);
  tail_k<<<dim3(512), dim3(256), 0, stream>>>(
      part1, b1, ln1_g, ln1_b, info, Wi, bi,
      Wa1, ba1, lna_g, lna_b, Wa2, ba2,
      Wo1, bo1, lno_g, lno_b, Wo2, bo2, outp);
}

// Round 5
// 91.869 us; speedup vs baseline: 2.5212x; 1.3523x over previous
//
#include <hip/hip_runtime.h>
#include <cstdint>

#define NPTS 65536
#define CCH  1024
#define BSEG 256
#define KSLOT 512
#define WROWS 32   // rows per segmax block window

typedef float v4f __attribute__((ext_vector_type(4)));

// monotonic float -> unsigned key; identity element is 0 (every real float maps > 0)
__device__ __forceinline__ unsigned ukey(float f) {
  int i = __float_as_int(f);
  return i >= 0 ? ((unsigned)i | 0x80000000u) : ~(unsigned)i;
}
// decode + apply the "len<K -> max(x,0)" padding rule; u==0 (empty segment) -> -inf -> relu -> 0
__device__ __forceinline__ float udec(unsigned u, bool rl) {
  float v;
  if (u >= 0x80000000u) v = __int_as_float((int)(u & 0x7FFFFFFFu));
  else                  v = __int_as_float((int)~u);
  if (u == 0u) v = -__builtin_inff();
  if (rl) v = fmaxf(v, 0.0f);
  return v;
}
__device__ __forceinline__ v4f vmax4(v4f a, v4f b) {
  v4f r;
  r.x = fmaxf(a.x, b.x); r.y = fmaxf(a.y, b.y);
  r.z = fmaxf(a.z, b.z); r.w = fmaxf(a.w, b.w);
  return r;
}

// 2048 blocks x 256 threads (8 blocks/CU, 32 waves/CU); 32-row window, 8-deep float4 unroll.
__global__ __launch_bounds__(256) void segmax_k(const float* __restrict__ feat,
                                                const int* __restrict__ offsets,
                                                unsigned* __restrict__ keys) {
  int t = threadIdx.x;
  int col = t << 2;
  int row0 = blockIdx.x * WROWS;
  int row_end = row0 + WROWS;
  // first seg with offsets[seg] > row0
  int lo = 0, hi = BSEG - 1;
  while (lo < hi) { int mid = (lo + hi) >> 1; if (offsets[mid] > row0) hi = mid; else lo = mid + 1; }
  int seg = lo;
  int end = offsets[seg];
  const float NI = -__builtin_inff();
  v4f m; m.x = NI; m.y = NI; m.z = NI; m.w = NI;
  bool dirty = false;
  int r = row0;
  while (r < row_end) {
    while (r >= end) {
      if (dirty) {
        unsigned* kp = keys + (size_t)seg * CCH + col;
        atomicMax(kp + 0, ukey(m.x));
        atomicMax(kp + 1, ukey(m.y));
        atomicMax(kp + 2, ukey(m.z));
        atomicMax(kp + 3, ukey(m.w));
        m.x = NI; m.y = NI; m.z = NI; m.w = NI;
        dirty = false;
      }
      ++seg;
      end = offsets[seg];
    }
    int stop = min(row_end, end);
    const float* p = feat + (size_t)r * CCH + col;
    for (; r + 8 <= stop; r += 8) {
      v4f v[8];
#pragma unroll
      for (int j = 0; j < 8; ++j) v[j] = *(const v4f*)(p + (size_t)j * CCH);
      p += 8 * CCH;
#pragma unroll
      for (int d = 4; d; d >>= 1)
#pragma unroll
        for (int j = 0; j < d; ++j) v[j] = vmax4(v[j], v[j + d]);
      m = vmax4(m, v[0]);
    }
    for (; r < stop; ++r) {
      v4f v = *(const v4f*)(p);
      p += CCH;
      m = vmax4(m, v);
    }
    dirty = true;
  }
  if (dirty) {
    unsigned* kp = keys + (size_t)seg * CCH + col;
    atomicMax(kp + 0, ukey(m.x));
    atomicMax(kp + 1, ukey(m.y));
    atomicMax(kp + 2, ukey(m.z));
    atomicMax(kp + 3, ukey(m.w));
  }
}

// GEMM1 fused with key-decode + features d_out write.
// grid (8,4,8): bx = 64-col tile, by = 64-row tile, bz = K-chunk (128 wide, 4 steps).
// bx==0 blocks write the decoded A slice (rows by*64..+64, cols bz*128..+128).
__global__ __launch_bounds__(256) void gemm1_fused(
    const unsigned* __restrict__ keys, const int* __restrict__ offsets,
    const float* __restrict__ W1, float* __restrict__ features,
    float* __restrict__ part1) {
  __shared__ float As[32][68];
  __shared__ float Ws[32][68];
  int bx = blockIdx.x, by = blockIdx.y, bz = blockIdx.z;
  int t = threadIdx.x;
  int tx = t & 15, ty = t >> 4;
  int lr = t >> 3;          // 0..31
  int lk = (t & 7) << 2;    // 0,4,...,28
  int row0 = by * 64 + lr, row1 = row0 + 32;
  int len0 = offsets[row0] - (row0 ? offsets[row0 - 1] : 0);
  int len1 = offsets[row1] - offsets[row1 - 1];
  bool rl0 = len0 < KSLOT, rl1 = len1 < KSLOT;
  const unsigned* K0 = keys + (size_t)row0 * CCH + lk;
  const unsigned* K1 = keys + (size_t)row1 * CCH + lk;
  int c0 = bx * 64 + lr, c1 = c0 + 32;
  const float* Wr0 = W1 + (size_t)c0 * CCH + lk;
  const float* Wr1 = W1 + (size_t)c1 * CCH + lk;
  float acc[4][4] = {};
  for (int s = 0; s < 4; ++s) {
    int k0 = (bz * 4 + s) << 5;
    uint4 ua = *(const uint4*)(K0 + k0);
    uint4 ub = *(const uint4*)(K1 + k0);
    float4 w0 = *(const float4*)(Wr0 + k0);
    float4 w1 = *(const float4*)(Wr1 + k0);
    float4 a0 = make_float4(udec(ua.x, rl0), udec(ua.y, rl0), udec(ua.z, rl0), udec(ua.w, rl0));
    float4 a1 = make_float4(udec(ub.x, rl1), udec(ub.y, rl1), udec(ub.z, rl1), udec(ub.w, rl1));
    if (bx == 0) {
      *(float4*)(features + (size_t)row0 * CCH + k0 + lk) = a0;
      *(float4*)(features + (size_t)row1 * CCH + k0 + lk) = a1;
    }
    __syncthreads();
    As[lk + 0][lr] = a0.x; As[lk + 1][lr] = a0.y; As[lk + 2][lr] = a0.z; As[lk + 3][lr] = a0.w;
    As[lk + 0][lr + 32] = a1.x; As[lk + 1][lr + 32] = a1.y; As[lk + 2][lr + 32] = a1.z; As[lk + 3][lr + 32] = a1.w;
    Ws[lk + 0][lr] = w0.x; Ws[lk + 1][lr] = w0.y; Ws[lk + 2][lr] = w0.z; Ws[lk + 3][lr] = w0.w;
    Ws[lk + 0][lr + 32] = w1.x; Ws[lk + 1][lr + 32] = w1.y; Ws[lk + 2][lr + 32] = w1.z; Ws[lk + 3][lr + 32] = w1.w;
    __syncthreads();
#pragma unroll
    for (int kk = 0; kk < 32; ++kk) {
      float4 av = *(const float4*)&As[kk][ty << 2];
      float4 wv = *(const float4*)&Ws[kk][tx << 2];
      acc[0][0] += av.x * wv.x; acc[0][1] += av.x * wv.y; acc[0][2] += av.x * wv.z; acc[0][3] += av.x * wv.w;
      acc[1][0] += av.y * wv.x; acc[1][1] += av.y * wv.y; acc[1][2] += av.y * wv.z; acc[1][3] += av.y * wv.w;
      acc[2][0] += av.z * wv.x; acc[2][1] += av.z * wv.y; acc[2][2] += av.z * wv.z; acc[2][3] += av.z * wv.w;
      acc[3][0] += av.w * wv.x; acc[3][1] += av.w * wv.y; acc[3][2] += av.w * wv.z; acc[3][3] += av.w * wv.w;
    }
  }
  float* op = part1 + (size_t)bz * 131072 + (size_t)(by * 64 + (ty << 2)) * 512 + bx * 64 + (tx << 2);
#pragma unroll
  for (int i = 0; i < 4; ++i)
    *(float4*)(op + (size_t)i * 512) = make_float4(acc[i][0], acc[i][1], acc[i][2], acc[i][3]);
}

// per-row: sum 8 K-partials + b1 -> LN(512) -> ReLU -> x[:,0:512]; info layer -> x[:,512:544]
__global__ __launch_bounds__(256) void ln1_x_k(
    const float* __restrict__ part1, const float* __restrict__ b1,
    const float* __restrict__ g, const float* __restrict__ be,
    const float* __restrict__ info, const float* __restrict__ Wi, const float* __restrict__ bi,
    float* __restrict__ x) {
  int b = blockIdx.x, t = threadIdx.x;
  int wv = t >> 6, ln = t & 63;
  __shared__ float red[2][4];
  __shared__ float stats[2];
  const float* p = part1 + (size_t)b * 512;
  float z0 = b1[t], z1 = b1[t + 256];
#pragma unroll
  for (int j = 0; j < 8; ++j) {
    z0 += p[(size_t)j * 131072 + t];
    z1 += p[(size_t)j * 131072 + 256 + t];
  }
  float s = z0 + z1, q = z0 * z0 + z1 * z1;
#pragma unroll
  for (int o = 32; o; o >>= 1) { s += __shfl_down(s, o); q += __shfl_down(q, o); }
  if (ln == 0) { red[0][wv] = s; red[1][wv] = q; }
  __syncthreads();
  if (t == 0) {
    float S = red[0][0] + red[0][1] + red[0][2] + red[0][3];
    float Q = red[1][0] + red[1][1] + red[1][2] + red[1][3];
    float mean = S * (1.f / 512.f);
    float var = Q * (1.f / 512.f) - mean * mean;
    stats[0] = mean; stats[1] = rsqrtf(var + 1e-5f);
  }
  __syncthreads();
  float mean = stats[0], rstd = stats[1];
  x[b * 544 + t]       = fmaxf((z0 - mean) * rstd * g[t]       + be[t],       0.f);
  x[b * 544 + t + 256] = fmaxf((z1 - mean) * rstd * g[t + 256] + be[t + 256], 0.f);
  if (t < 32) {
    float i0 = info[b * 3], i1 = info[b * 3 + 1], i2 = info[b * 3 + 2];
    x[b * 544 + 512 + t] = bi[t] + Wi[t * 3] * i0 + Wi[t * 3 + 1] * i1 + Wi[t * 3 + 2] * i2;
  }
}

// layer-2 NT GEMM: x(256x544) @ [Wa1;Wo1]^T -> part2 K-slabs. grid (8,4,4), steps {5,5,5,2}.
__global__ __launch_bounds__(256) void gemm_nt_part(
    const float* __restrict__ A, int lda,
    const float* __restrict__ Wlo, const float* __restrict__ Whi, int nlo, int ldw,
    float* __restrict__ part, int Ktot, int steps_per_chunk) {
  __shared__ float As[32][68];
  __shared__ float Ws[32][68];
  int bx = blockIdx.x, by = blockIdx.y, bz = blockIdx.z;
  int t = threadIdx.x;
  int tx = t & 15, ty = t >> 4;
  int steps_total = Ktot >> 5;
  int step0 = bz * steps_per_chunk;
  int nsteps = min(steps_per_chunk, steps_total - step0);
  int lr = t >> 3;
  int lk = (t & 7) << 2;
  const float* Arow0 = A + (size_t)(by * 64 + lr) * lda + lk;
  const float* Arow1 = Arow0 + (size_t)32 * lda;
  int c0 = bx * 64 + lr;
  int c1 = c0 + 32;
  const float* Wrow0 = (c0 < nlo ? Wlo + (size_t)c0 * ldw : Whi + (size_t)(c0 - nlo) * ldw) + lk;
  const float* Wrow1 = (c1 < nlo ? Wlo + (size_t)c1 * ldw : Whi + (size_t)(c1 - nlo) * ldw) + lk;
  float acc[4][4] = {};
  for (int s = 0; s < nsteps; ++s) {
    int k0 = (step0 + s) << 5;
    float4 a0 = *(const float4*)(Arow0 + k0);
    float4 a1 = *(const float4*)(Arow1 + k0);
    float4 w0 = *(const float4*)(Wrow0 + k0);
    float4 w1 = *(const float4*)(Wrow1 + k0);
    __syncthreads();
    As[lk + 0][lr] = a0.x; As[lk + 1][lr] = a0.y; As[lk + 2][lr] = a0.z; As[lk + 3][lr] = a0.w;
    As[lk + 0][lr + 32] = a1.x; As[lk + 1][lr + 32] = a1.y; As[lk + 2][lr + 32] = a1.z; As[lk + 3][lr + 32] = a1.w;
    Ws[lk + 0][lr] = w0.x; Ws[lk + 1][lr] = w0.y; Ws[lk + 2][lr] = w0.z; Ws[lk + 3][lr] = w0.w;
    Ws[lk + 0][lr + 32] = w1.x; Ws[lk + 1][lr + 32] = w1.y; Ws[lk + 2][lr + 32] = w1.z; Ws[lk + 3][lr + 32] = w1.w;
    __syncthreads();
#pragma unroll
    for (int kk = 0; kk < 32; ++kk) {
      float4 av = *(const float4*)&As[kk][ty << 2];
      float4 wv = *(const float4*)&Ws[kk][tx << 2];
      acc[0][0] += av.x * wv.x; acc[0][1] += av.x * wv.y; acc[0][2] += av.x * wv.z; acc[0][3] += av.x * wv.w;
      acc[1][0] += av.y * wv.x; acc[1][1] += av.y * wv.y; acc[1][2] += av.y * wv.z; acc[1][3] += av.y * wv.w;
      acc[2][0] += av.z * wv.x; acc[2][1] += av.z * wv.y; acc[2][2] += av.z * wv.z; acc[2][3] += av.z * wv.w;
      acc[3][0] += av.w * wv.x; acc[3][1] += av.w * wv.y; acc[3][2] += av.w * wv.z; acc[3][3] += av.w * wv.w;
    }
  }
  float* op = part + (size_t)bz * 131072 + (size_t)(by * 64 + (ty << 2)) * 512 + bx * 64 + (tx << 2);
#pragma unroll
  for (int i = 0; i < 4; ++i)
    *(float4*)(op + (size_t)i * 512) = make_float4(acc[i][0], acc[i][1], acc[i][2], acc[i][3]);
}

// per-row: sum 4 K-partials + bias -> LN(256) -> ReLU for both heads, then 6+18 dot products.
__global__ __launch_bounds__(256) void heads_k(
    const float* __restrict__ part2,
    const float* __restrict__ ba1, const float* __restrict__ ga, const float* __restrict__ bea,
    const float* __restrict__ Wa2, const float* __restrict__ ba2,
    const float* __restrict__ bo1, const float* __restrict__ go, const float* __restrict__ beo,
    const float* __restrict__ Wo2, const float* __restrict__ bo2,
    float* __restrict__ outp) {
  int b = blockIdx.x, t = threadIdx.x;
  int wv = t >> 6, ln = t & 63;
  __shared__ float h[512];
  __shared__ float red[4][4];
  __shared__ float stats[4];
  const float* p0 = part2 + (size_t)b * 512;
  float za = ba1[t], zo = bo1[t];
#pragma unroll
  for (int j = 0; j < 4; ++j) {
    za += p0[(size_t)j * 131072 + t];
    zo += p0[(size_t)j * 131072 + 256 + t];
  }
  float sa = za, qa = za * za, so = zo, qo = zo * zo;
#pragma unroll
  for (int o = 32; o; o >>= 1) {
    sa += __shfl_down(sa, o); qa += __shfl_down(qa, o);
    so += __shfl_down(so, o); qo += __shfl_down(qo, o);
  }
  if (ln == 0) { red[wv][0] = sa; red[wv][1] = qa; red[wv][2] = so; red[wv][3] = qo; }
  __syncthreads();
  if (t == 0) {
    float Sa = red[0][0] + red[1][0] + red[2][0] + red[3][0];
    float Qa = red[0][1] + red[1][1] + red[2][1] + red[3][1];
    float So = red[0][2] + red[1][2] + red[2][2] + red[3][2];
    float Qo = red[0][3] + red[1][3] + red[2][3] + red[3][3];
    float ma = Sa * (1.f / 256.f), va = Qa * (1.f / 256.f) - ma * ma;
    float mo = So * (1.f / 256.f), vo = Qo * (1.f / 256.f) - mo * mo;
    stats[0] = ma; stats[1] = rsqrtf(va + 1e-5f);
    stats[2] = mo; stats[3] = rsqrtf(vo + 1e-5f);
  }
  __syncthreads();
  h[t]       = fmaxf((za - stats[0]) * stats[1] * ga[t] + bea[t], 0.f);
  h[256 + t] = fmaxf((zo - stats[2]) * stats[3] * go[t] + beo[t], 0.f);
  __syncthreads();
  const float* hh = (wv == 0) ? h : (h + 256);
  const float* W2 = (wv == 0) ? Wa2 : Wo2;
  const float* b2 = (wv == 0) ? ba2 : bo2;
  int o0 = (wv == 0) ? 0 : (wv - 1) * 6;
  int base = (wv == 0) ? (262144 + b * 6) : (263680 + b * 18);
  float h0 = hh[ln], h1 = hh[64 + ln], h2v = hh[128 + ln], h3 = hh[192 + ln];
#pragma unroll
  for (int oo = 0; oo < 6; ++oo) {
    int o = o0 + oo;
    const float* w = W2 + o * 256;
    float pr = h0 * w[ln] + h1 * w[64 + ln] + h2v * w[128 + ln] + h3 * w[192 + ln];
#pragma unroll
    for (int d = 32; d; d >>= 1) pr += __shfl_down(pr, d);
    if (ln == 0) outp[base + o] = pr + b2[o];
  }
}

extern "C" void kernel_launch(void* const* d_in, const int* in_sizes, int n_in,
                              void* d_out, int out_size, void* d_ws, size_t ws_size,
                              hipStream_t stream) {
  const float* feat   = (const float*)d_in[0];
  const float* info   = (const float*)d_in[1];
  const int*   offs   = (const int*)d_in[2];
  const float* W1     = (const float*)d_in[3];
  const float* b1     = (const float*)d_in[4];
  const float* ln1_g  = (const float*)d_in[5];
  const float* ln1_b  = (const float*)d_in[6];
  const float* Wi     = (const float*)d_in[7];
  const float* bi     = (const float*)d_in[8];
  const float* Wa1    = (const float*)d_in[9];
  const float* ba1    = (const float*)d_in[10];
  const float* lna_g  = (const float*)d_in[11];
  const float* lna_b  = (const float*)d_in[12];
  const float* Wa2    = (const float*)d_in[13];
  const float* ba2    = (const float*)d_in[14];
  const float* Wo1    = (const float*)d_in[15];
  const float* bo1    = (const float*)d_in[16];
  const float* lno_g  = (const float*)d_in[17];
  const float* lno_b  = (const float*)d_in[18];
  const float* Wo2    = (const float*)d_in[19];
  const float* bo2    = (const float*)d_in[20];

  char* ws = (char*)d_ws;
  float*    part1 = (float*)ws;                    // 8*256*512*4 = 4 MB
  float*    part2 = (float*)(ws + (4u << 20));     // 4*256*512*4 = 2 MB
  float*    xbuf  = (float*)(ws + (6u << 20));     // 256*544*4 ≈ 557 KB
  unsigned* keys  = (unsigned*)(ws + (7u << 20));  // 256*1024*4 = 1 MB
  float* features = (float*)d_out;                 // [0, 262144)
  float* outp     = (float*)d_out;                 // pred @262144, offset @263680

  hipMemsetAsync(keys, 0, (size_t)BSEG * CCH * sizeof(unsigned), stream);
  segmax_k<<<dim3(NPTS / WROWS), dim3(256), 0, stream>>>(feat, offs, keys);
  gemm1_fused<<<dim3(8, 4, 8), dim3(256), 0, stream>>>(keys, offs, W1, features, part1);
  ln1_x_k<<<dim3(256), dim3(256), 0, stream>>>(part1, b1, ln1_g, ln1_b, info, Wi, bi, xbuf);
  gemm_nt_part<<<dim3(8, 4, 4), dim3(256), 0, stream>>>(
      xbuf, 544, Wa1, Wo1, 256, 544, part2, 544, 5);
  heads_k<<<dim3(256), dim3(256), 0, stream>>>(
      part2, ba1, lna_g, lna_b, Wa2, ba2, bo1, lno_g, lno_b, Wo2, bo2, outp);
}